// Round 11
// baseline (201.622 us; speedup 1.0000x reference)
//
#include <hip/hip_runtime.h>
#include <hip/hip_bf16.h>
#include <hip/hip_fp16.h>
#include <stdint.h>

// Problem constants (B=2, T=2048, D=1024, H=16, hd=64)
#define B_    2
#define T_    2048
#define DM    1024
#define NH    16
#define HD    64
#define M_    (B_ * T_)      // 4096 rows of X
#define N_QKV (3 * DM)       // 3072

typedef __attribute__((ext_vector_type(8))) __bf16 bf16x8;
typedef __attribute__((ext_vector_type(4))) float  v4f;
typedef __attribute__((ext_vector_type(2))) __fp16 fp16x2;   // cvt_pkrtz return type
typedef __attribute__((ext_vector_type(4))) _Float16 h4;
typedef __attribute__((ext_vector_type(8))) _Float16 h8;
typedef __hip_bfloat16 bf16;

// Q is PRE-SCALED by log2(e)/64 in the QKV epilogue, so softmax is
// P = exp2(S') with S' = (Q*c)K^T directly -- no per-element multiply.
#define EXP_SC 0.022542110013890053f

// s_waitcnt immediates (gfx9 encoding: vmcnt[3:0], expcnt[6:4], lgkmcnt[11:8])
#define WAITCNT_VM4 0x0F74   // vmcnt(4), lgkm/exp unwaited
#define WAITCNT_VM0 0x0F70   // vmcnt(0)

// ---- async global->LDS, 16B per lane (LDS dest must be lane-contiguous) ----
__device__ __forceinline__ void gld_lds16(const void* g, void* l) {
  __builtin_amdgcn_global_load_lds(
      (const __attribute__((address_space(1))) void*)(g),
      (__attribute__((address_space(3))) void*)(l), 16, 0, 0);
}

// XOR-swizzle: granule g' in LDS holds global granule g = g' ^ (row & mask).
// Keeps staging lane-contiguous while rotating banks per row for reads.

// ---------------- cast fp32 -> bf16 (vectorized) ----------------
__global__ void cast_f32_bf16(const float* __restrict__ in, bf16* __restrict__ out) {
  int i = (blockIdx.x * 256 + threadIdx.x) * 4;
  float4 v = *(const float4*)(in + i);
  union { bf16 h[4]; ushort4 u; } r;
  r.h[0] = __float2bfloat16(v.x); r.h[1] = __float2bfloat16(v.y);
  r.h[2] = __float2bfloat16(v.z); r.h[3] = __float2bfloat16(v.w);
  *(ushort4*)(out + i) = r.u;
}

// ---------------- transpose + cast: in[R][C] fp32 -> out[C][R] bf16 ----------------
__global__ void transpose_cast(const float* __restrict__ in, bf16* __restrict__ out,
                               int R, int C) {
  __shared__ float tile[32][33];
  int c0 = blockIdx.x * 32, r0 = blockIdx.y * 32;
  int tx = threadIdx.x, ty = threadIdx.y;
  #pragma unroll
  for (int i = ty; i < 32; i += 8)
    tile[i][tx] = in[(size_t)(r0 + i) * C + c0 + tx];
  __syncthreads();
  #pragma unroll
  for (int i = ty; i < 32; i += 8)
    out[(size_t)(c0 + i) * R + r0 + tx] = __float2bfloat16(tile[tx][i]);
}

// ---------------- transpose V: in[bh][t][d] f16 -> out[bh][d][t] f16 ----------------
__global__ __launch_bounds__(256) void transpose_v(
    const _Float16* __restrict__ in, _Float16* __restrict__ out) {
  __shared__ _Float16 tl[64][72];   // +8 pad
  const int tid = threadIdx.x, bh = blockIdx.y, t0 = blockIdx.x * 64;
  const size_t ib = (size_t)bh * T_ * HD, ob = (size_t)bh * HD * T_;
  #pragma unroll
  for (int i = 0; i < 2; ++i) {
    int flat = (i * 256 + tid) * 8;   // 4096 elems total (64x64 tile)
    int r = flat >> 6, c = flat & 63;
    *(uint4*)(&tl[r][c]) = *(const uint4*)(in + ib + (size_t)(t0 + r) * HD + c);
  }
  __syncthreads();
  int d = tid >> 2, c0 = (tid & 3) * 16;
  #pragma unroll
  for (int j = 0; j < 16; j += 8) {
    union { _Float16 h[8]; uint4 u; } pk;
    #pragma unroll
    for (int k2 = 0; k2 < 8; ++k2) pk.h[k2] = tl[c0 + j + k2][d];
    *(uint4*)(out + ob + (size_t)d * T_ + t0 + c0 + j) = pk.u;
  }
}

// ---------------- 128x128 BT-GEMM (A[M][K] bf16, BT[N][K] bf16) ----------------
// XOR-swizzled LDS. MODE 0: C fp32 plain store. MODE 1: QKV split (Q bf16
// PRE-SCALED by EXP_SC, K bf16, V f16, all [bh][t][d]; V transposed later).
template <int MODE>
__global__ __launch_bounds__(256) void gemm_bt(
    const bf16* __restrict__ A, const bf16* __restrict__ BT,
    float* __restrict__ Cf, bf16* __restrict__ qb, bf16* __restrict__ kb,
    _Float16* __restrict__ vb, int M, int N, int K) {
  __shared__ bf16 As[128 * 64];   // [m][g-swizzled k]
  __shared__ bf16 Bs[128 * 64];   // [n][g-swizzled k]
  const int tid = threadIdx.x;
  const int l = tid & 63, w = tid >> 6;
  const int wm = w >> 1, wn = w & 1;          // 2x2 wave grid, 64x64 C each
  const int m0 = blockIdx.y * 128, n0 = blockIdx.x * 128;
  const int fr = l & 15;                      // fragment row (m or n)
  const int lg = l >> 4;                      // lane granule group 0..3

  v4f acc[4][4] = {};

  for (int kt = 0; kt < K; kt += 64) {
    __syncthreads();
    #pragma unroll
    for (int i = 0; i < 4; ++i) {
      int p = i * 256 + tid;                  // granule index 0..1023
      int row = p >> 3, g = (p & 7) ^ (row & 7);
      gld_lds16(A + (size_t)(m0 + row) * K + kt + g * 8, As + p * 8);
      gld_lds16(BT + (size_t)(n0 + row) * K + kt + g * 8, Bs + p * 8);
    }
    __syncthreads();
    #pragma unroll
    for (int kk = 0; kk < 64; kk += 32) {
      const int gl = (kk >> 3) + lg;          // logical granule 0..7
      bf16x8 af[4], bfr[4];
      #pragma unroll
      for (int i = 0; i < 4; ++i) {
        int row = wm * 64 + i * 16 + fr;
        af[i] = *(const bf16x8*)(As + row * 64 + (gl ^ (fr & 7)) * 8);
      }
      #pragma unroll
      for (int i = 0; i < 4; ++i) {
        int row = wn * 64 + i * 16 + fr;
        bfr[i] = *(const bf16x8*)(Bs + row * 64 + (gl ^ (fr & 7)) * 8);
      }
      #pragma unroll
      for (int mi = 0; mi < 4; ++mi)
        #pragma unroll
        for (int ni = 0; ni < 4; ++ni)
          acc[mi][ni] = __builtin_amdgcn_mfma_f32_16x16x32_bf16(
              af[mi], bfr[ni], acc[mi][ni], 0, 0, 0);
    }
  }

  // Epilogue. C/D layout: col = lane&15, row = (lane>>4)*4 + reg.
  #pragma unroll
  for (int mi = 0; mi < 4; ++mi) {
    #pragma unroll
    for (int ni = 0; ni < 4; ++ni) {
      #pragma unroll
      for (int r = 0; r < 4; ++r) {
        int gm = m0 + wm * 64 + mi * 16 + (l >> 4) * 4 + r;
        int gn = n0 + wn * 64 + ni * 16 + (l & 15);
        float v = acc[mi][ni][r];
        if constexpr (MODE == 0) {
          Cf[(size_t)gm * N + gn] = v;
        } else {
          int b = gm >> 11, t = gm & 2047;            // T=2048
          int s = gn >> 10, h = (gn >> 6) & 15, d = gn & 63;
          size_t bh = (size_t)(b * NH + h);
          if (s == 0)      qb[(bh * T_ + t) * HD + d] = __float2bfloat16(v * EXP_SC);
          else if (s == 1) kb[(bh * T_ + t) * HD + d] = __float2bfloat16(v);
          else             vb[(bh * T_ + t) * HD + d] = (_Float16)v;
        }
      }
    }
  }
}

// ---------------- 128x64 BT-GEMM for the projection ----------------
__global__ __launch_bounds__(256) void gemm_bt_n64(
    const bf16* __restrict__ A, const bf16* __restrict__ BT,
    float* __restrict__ Cf, int M, int N, int K) {
  __shared__ bf16 As[128 * 64];   // 16KB
  __shared__ bf16 Bs[64 * 64];    //  8KB
  const int tid = threadIdx.x;
  const int l = tid & 63, w = tid >> 6;
  const int wm = w >> 1, wn = w & 1;          // 64m x 32n per wave
  const int m0 = blockIdx.y * 128, n0 = blockIdx.x * 64;
  const int fr = l & 15;
  const int lg = l >> 4;

  v4f acc[4][2] = {};

  for (int kt = 0; kt < K; kt += 64) {
    __syncthreads();
    #pragma unroll
    for (int i = 0; i < 4; ++i) {
      int p = i * 256 + tid;
      int row = p >> 3, g = (p & 7) ^ (row & 7);
      gld_lds16(A + (size_t)(m0 + row) * K + kt + g * 8, As + p * 8);
    }
    #pragma unroll
    for (int i = 0; i < 2; ++i) {
      int p = i * 256 + tid;
      int row = p >> 3, g = (p & 7) ^ (row & 7);
      gld_lds16(BT + (size_t)(n0 + row) * K + kt + g * 8, Bs + p * 8);
    }
    __syncthreads();
    #pragma unroll
    for (int kk = 0; kk < 64; kk += 32) {
      const int gl = (kk >> 3) + lg;
      bf16x8 af[4], bfr[2];
      #pragma unroll
      for (int i = 0; i < 4; ++i) {
        int row = wm * 64 + i * 16 + fr;
        af[i] = *(const bf16x8*)(As + row * 64 + (gl ^ (fr & 7)) * 8);
      }
      #pragma unroll
      for (int i = 0; i < 2; ++i) {
        int row = wn * 32 + i * 16 + fr;
        bfr[i] = *(const bf16x8*)(Bs + row * 64 + (gl ^ (fr & 7)) * 8);
      }
      #pragma unroll
      for (int mi = 0; mi < 4; ++mi)
        #pragma unroll
        for (int ni = 0; ni < 2; ++ni)
          acc[mi][ni] = __builtin_amdgcn_mfma_f32_16x16x32_bf16(
              af[mi], bfr[ni], acc[mi][ni], 0, 0, 0);
    }
  }

  #pragma unroll
  for (int mi = 0; mi < 4; ++mi)
    #pragma unroll
    for (int ni = 0; ni < 2; ++ni)
      #pragma unroll
      for (int r = 0; r < 4; ++r) {
        int gm = m0 + wm * 64 + mi * 16 + (l >> 4) * 4 + r;
        int gn = n0 + wn * 32 + ni * 16 + (l & 15);
        Cf[(size_t)gm * N + gn] = acc[mi][ni][r];
      }
}

// ---------------- fused attention: dbuf Kt=64 + fine-grained vmcnt ----------
// Key-split waves (qh=w&1, kh=w>>1): 64 q x 32 keys per wave per 64-key tile.
// Double-buffered K/V staging: per tile, prefetch t+1 into the other buffer
// AFTER a raw s_barrier (WAR-safe), then s_waitcnt vmcnt(4) waits only the
// CURRENT tile's 4 loads (prefetch stays in flight across the second raw
// s_barrier) -- the AITER-style pipeline that __syncthreads can't express.
// S^T C-layout -> in-register exp2 (Q pre-scaled) -> packed b64 P store ->
// full-rate K=32 f16 PV; row sums via ones-B MFMA; additive key-half combine.
__global__ __launch_bounds__(256) void flash_attn(
    const bf16* __restrict__ Qg, const bf16* __restrict__ Kg,
    const _Float16* __restrict__ VTg, bf16* __restrict__ Og) {
  __shared__ char smem[53248];
  bf16*     KsB = (bf16*)smem;                // [2][64*64] bf16, 16KB
  _Float16* VsB = (_Float16*)(smem + 16384);  // [2][64*64] f16, 16KB
  _Float16 (*Ps)[40] = (_Float16(*)[40])(smem + 32768); // [4*64][40], 20KB
  float*    Obuf = (float*)smem;              // combine alias [2][64][68]
  float*    Lbuf = (float*)(smem + 34816);    // combine alias [2][64]

  const int tid = threadIdx.x, l = tid & 63, w = tid >> 6;
  const int qh = w & 1, kh = w >> 1;
  const int fr = l & 15, fk = (l >> 4) * 8, g4 = (l >> 4) * 4, lg = l >> 4;
  const int bh = blockIdx.y, qt = blockIdx.x;
  const int q0 = qt * 128 + qh * 64;
  const size_t base  = (size_t)bh * T_ * HD;
  const size_t baseV = (size_t)bh * HD * T_;
  _Float16 (*Pw)[40] = Ps + w * 64;

  // Q fragments (B-operand of S^T) in registers, loaded once. Pre-scaled.
  bf16x8 qB[4][2];
  #pragma unroll
  for (int qf = 0; qf < 4; ++qf)
    #pragma unroll
    for (int kki = 0; kki < 2; ++kki)
      qB[qf][kki] = *(const bf16x8*)(
          Qg + base + (size_t)(q0 + qf * 16 + fr) * HD + kki * 32 + fk);

  h8 ones;
  #pragma unroll
  for (int j = 0; j < 8; ++j) ones[j] = (_Float16)1.0f;

  v4f o[4][4] = {};
  v4f lacc[4] = {};

  // Prologue: stage tile 0 into buffer 0 (4 gld_lds16 per thread per tile).
  #pragma unroll
  for (int i = 0; i < 2; ++i) {
    int p = i * 256 + tid;
    int row = p >> 3, g = (p & 7) ^ (row & 7);
    gld_lds16(Kg + base + (size_t)row * HD + g * 8, KsB + p * 8);
    gld_lds16(VTg + baseV + (size_t)row * T_ + g * 8, VsB + p * 8);
  }

  for (int t = 0; t < 32; ++t) {
    const int cur = t & 1;
    bf16*     Kc = KsB + cur * 4096;
    _Float16* Vc = VsB + cur * 4096;

    // (1) all waves done computing on buffer (1-cur) -> free to overwrite
    __asm__ volatile("" ::: "memory");
    __builtin_amdgcn_s_barrier();
    __asm__ volatile("" ::: "memory");

    if (t < 31) {
      const int ktn = (t + 1) * 64;
      bf16*     Kn = KsB + (1 - cur) * 4096;
      _Float16* Vn = VsB + (1 - cur) * 4096;
      #pragma unroll
      for (int i = 0; i < 2; ++i) {
        int p = i * 256 + tid;
        int row = p >> 3, g = (p & 7) ^ (row & 7);
        gld_lds16(Kg + base + (size_t)(ktn + row) * HD + g * 8, Kn + p * 8);
        gld_lds16(VTg + baseV + (size_t)row * T_ + ktn + g * 8, Vn + p * 8);
      }
      __asm__ volatile("" ::: "memory");
      __builtin_amdgcn_s_waitcnt(WAITCNT_VM4);  // current tile landed; prefetch in flight
    } else {
      __asm__ volatile("" ::: "memory");
      __builtin_amdgcn_s_waitcnt(WAITCNT_VM0);
    }
    // (2) everyone's current-tile loads are in LDS
    __asm__ volatile("" ::: "memory");
    __builtin_amdgcn_s_barrier();
    __asm__ volatile("" ::: "memory");

    // S^T on wave's 32 keys -> exp2 -> packed P -> PV (one 32-key chunk)
    #pragma unroll
    for (int kf = 0; kf < 2; ++kf) {
      const int krow = kh * 32 + kf * 16 + fr;
      v4f st[4] = {};
      #pragma unroll
      for (int kki = 0; kki < 2; ++kki) {
        bf16x8 ak = *(const bf16x8*)(
            Kc + krow * 64 + ((kki * 4 + lg) ^ (fr & 7)) * 8);
        #pragma unroll
        for (int qf = 0; qf < 4; ++qf)
          st[qf] = __builtin_amdgcn_mfma_f32_16x16x32_bf16(
              ak, qB[qf][kki], st[qf], 0, 0, 0);
      }
      #pragma unroll
      for (int qf = 0; qf < 4; ++qf) {
        union { fp16x2 p2[2]; h4 p4; } u;
        u.p2[0] = __builtin_amdgcn_cvt_pkrtz(
            __builtin_amdgcn_exp2f(st[qf][0]),
            __builtin_amdgcn_exp2f(st[qf][1]));
        u.p2[1] = __builtin_amdgcn_cvt_pkrtz(
            __builtin_amdgcn_exp2f(st[qf][2]),
            __builtin_amdgcn_exp2f(st[qf][3]));
        *(h4*)(&Pw[qf * 16 + fr][kf * 16 + g4]) = u.p4;
      }
    }
    h8 ap[4], bv[4];
    #pragma unroll
    for (int qf = 0; qf < 4; ++qf)
      ap[qf] = *(const h8*)(&Pw[qf * 16 + fr][fk]);
    #pragma unroll
    for (int nf = 0; nf < 4; ++nf) {
      int row = nf * 16 + fr;
      bv[nf] = *(const h8*)(Vc + row * 64 + ((kh * 4 + lg) ^ (fr & 7)) * 8);
    }
    #pragma unroll
    for (int qf = 0; qf < 4; ++qf) {
      lacc[qf] = __builtin_amdgcn_mfma_f32_16x16x32_f16(
          ap[qf], ones, lacc[qf], 0, 0, 0);
      #pragma unroll
      for (int nf = 0; nf < 4; ++nf)
        o[qf][nf] = __builtin_amdgcn_mfma_f32_16x16x32_f16(
            ap[qf], bv[nf], o[qf][nf], 0, 0, 0);
    }
  }

  // Combine key halves: waves 2,3 dump partials to LDS; waves 0,1 add + store.
  __syncthreads();           // full barrier; K/V/Ps dead, alias as Obuf/Lbuf
  if (w >= 2) {
    #pragma unroll
    for (int qf = 0; qf < 4; ++qf)
      #pragma unroll
      for (int r = 0; r < 4; ++r) {
        int row = qf * 16 + g4 + r;
        #pragma unroll
        for (int nf = 0; nf < 4; ++nf)
          Obuf[(qh * 64 + row) * 68 + nf * 16 + fr] = o[qf][nf][r];
        if (fr == 0) Lbuf[qh * 64 + row] = lacc[qf][r];
      }
  }
  __syncthreads();
  if (w < 2) {
    int b = bh >> 4, h = bh & 15;
    #pragma unroll
    for (int qf = 0; qf < 4; ++qf) {
      #pragma unroll
      for (int r = 0; r < 4; ++r) {
        int row = qf * 16 + g4 + r;
        float inv = 1.f / (lacc[qf][r] + Lbuf[qh * 64 + row]);
        int t = q0 + row;
        #pragma unroll
        for (int nf = 0; nf < 4; ++nf) {
          float val = o[qf][nf][r] + Obuf[(qh * 64 + row) * 68 + nf * 16 + fr];
          Og[((size_t)(b * T_ + t)) * DM + h * HD + nf * 16 + fr] =
              __float2bfloat16(val * inv);
        }
      }
    }
  }
}

extern "C" void kernel_launch(void* const* d_in, const int* in_sizes, int n_in,
                              void* d_out, int out_size, void* d_ws, size_t ws_size,
                              hipStream_t stream) {
  const float* x     = (const float*)d_in[0];
  const float* Wqkv  = (const float*)d_in[1];
  const float* Wproj = (const float*)d_in[2];
  float* out = (float*)d_out;
  char* ws = (char*)d_ws;

  // Workspace layout (48 MB total). Region 40-48MB double-used: first Vh
  // (f16 V [bh][t][d], consumed by transpose_v), then Ab (flash output).
  bf16*     Xb     = (bf16*)(ws);                        //  8 MB
  bf16*     WqkvT  = (bf16*)(ws + (size_t)( 8u << 20));  //  6 MB
  bf16*     WprojT = (bf16*)(ws + (size_t)(14u << 20));  //  2 MB
  bf16*     Qb     = (bf16*)(ws + (size_t)(16u << 20));  //  8 MB
  bf16*     Kb     = (bf16*)(ws + (size_t)(24u << 20));  //  8 MB
  _Float16* VTh    = (_Float16*)(ws + (size_t)(32u << 20)); // 8 MB
  _Float16* Vh     = (_Float16*)(ws + (size_t)(40u << 20)); // 8 MB (temp)
  bf16*     Ab     = (bf16*)(ws + (size_t)(40u << 20));  //  8 MB (overlay)

  cast_f32_bf16<<<(M_ * DM) / 1024, 256, 0, stream>>>(x, Xb);
  transpose_cast<<<dim3(N_QKV / 32, DM / 32), dim3(32, 8), 0, stream>>>(Wqkv, WqkvT, DM, N_QKV);
  transpose_cast<<<dim3(DM / 32, DM / 32), dim3(32, 8), 0, stream>>>(Wproj, WprojT, DM, DM);

  gemm_bt<1><<<dim3(N_QKV / 128, M_ / 128), 256, 0, stream>>>(
      Xb, WqkvT, nullptr, Qb, Kb, Vh, M_, N_QKV, DM);

  transpose_v<<<dim3(T_ / 64, B_ * NH), 256, 0, stream>>>(Vh, VTh);

  flash_attn<<<dim3(T_ / 128, B_ * NH), 256, 0, stream>>>(Qb, Kb, VTh, Ab);

  gemm_bt_n64<<<dim3(DM / 64, M_ / 128), 256, 0, stream>>>(
      Ab, WprojT, out, M_, DM, DM);
}

// Round 12
// 188.378 us; speedup vs baseline: 1.0703x; 1.0703x over previous
//
#include <hip/hip_runtime.h>
#include <hip/hip_bf16.h>
#include <hip/hip_fp16.h>
#include <stdint.h>

// Problem constants (B=2, T=2048, D=1024, H=16, hd=64)
#define B_    2
#define T_    2048
#define DM    1024
#define NH    16
#define HD    64
#define M_    (B_ * T_)      // 4096 rows of X
#define N_QKV (3 * DM)       // 3072

typedef __attribute__((ext_vector_type(8))) __bf16 bf16x8;
typedef __attribute__((ext_vector_type(4))) float  v4f;
typedef __attribute__((ext_vector_type(2))) __fp16 fp16x2;   // cvt_pkrtz return type
typedef __attribute__((ext_vector_type(4))) _Float16 h4;
typedef __attribute__((ext_vector_type(8))) _Float16 h8;
typedef __hip_bfloat16 bf16;

// Q is PRE-SCALED by log2(e)/64 in the QKV epilogue, so softmax is
// P = exp2(S') with S' = (Q*c)K^T directly -- no per-element multiply.
#define EXP_SC 0.022542110013890053f

// ---- async global->LDS, 16B per lane (LDS dest must be lane-contiguous) ----
__device__ __forceinline__ void gld_lds16(const void* g, void* l) {
  __builtin_amdgcn_global_load_lds(
      (const __attribute__((address_space(1))) void*)(g),
      (__attribute__((address_space(3))) void*)(l), 16, 0, 0);
}

// XOR-swizzle: granule g' in LDS holds global granule g = g' ^ (row & mask).
// Keeps staging lane-contiguous while rotating banks per row for reads.

// ---------------- fused prep: cast X + transpose both weights ----------------
// 1D grid, role by flat block id: [0,4096) cast X; [4096,7168) Wqkv^T;
// [7168,8192) Wproj^T. One dispatch instead of three (fewer serial gaps).
__global__ __launch_bounds__(256) void prep(
    const float* __restrict__ x, const float* __restrict__ Wqkv,
    const float* __restrict__ Wproj, bf16* __restrict__ Xb,
    bf16* __restrict__ WqkvT, bf16* __restrict__ WprojT) {
  const int f = blockIdx.x;
  if (f < 4096) {               // cast X -> bf16
    int i = (f * 256 + threadIdx.x) * 4;
    float4 v = *(const float4*)(x + i);
    union { bf16 h[4]; ushort4 u; } r;
    r.h[0] = __float2bfloat16(v.x); r.h[1] = __float2bfloat16(v.y);
    r.h[2] = __float2bfloat16(v.z); r.h[3] = __float2bfloat16(v.w);
    *(ushort4*)(Xb + i) = r.u;
    return;
  }
  __shared__ float tile[32][33];
  const float* in; bf16* out; int C, bx, by;
  if (f < 4096 + 3072) { int g = f - 4096; bx = g % 96; by = g / 96;
                         in = Wqkv;  out = WqkvT;  C = N_QKV; }
  else                 { int g = f - 7168; bx = g % 32; by = g / 32;
                         in = Wproj; out = WprojT; C = DM; }
  const int R = DM;
  int tx = threadIdx.x & 31, ty = threadIdx.x >> 5;
  int c0 = bx * 32, r0 = by * 32;
  #pragma unroll
  for (int i = ty; i < 32; i += 8)
    tile[i][tx] = in[(size_t)(r0 + i) * C + c0 + tx];
  __syncthreads();
  #pragma unroll
  for (int i = ty; i < 32; i += 8)
    out[(size_t)(c0 + i) * R + r0 + tx] = __float2bfloat16(tile[tx][i]);
}

// ---------------- transpose V: in[bh][t][d] f16 -> out[bh][d][t] f16 ----------------
__global__ __launch_bounds__(256) void transpose_v(
    const _Float16* __restrict__ in, _Float16* __restrict__ out) {
  __shared__ _Float16 tl[64][72];   // +8 pad
  const int tid = threadIdx.x, bh = blockIdx.y, t0 = blockIdx.x * 64;
  const size_t ib = (size_t)bh * T_ * HD, ob = (size_t)bh * HD * T_;
  #pragma unroll
  for (int i = 0; i < 2; ++i) {
    int flat = (i * 256 + tid) * 8;   // 4096 elems total (64x64 tile)
    int r = flat >> 6, c = flat & 63;
    *(uint4*)(&tl[r][c]) = *(const uint4*)(in + ib + (size_t)(t0 + r) * HD + c);
  }
  __syncthreads();
  int d = tid >> 2, c0 = (tid & 3) * 16;
  #pragma unroll
  for (int j = 0; j < 16; j += 8) {
    union { _Float16 h[8]; uint4 u; } pk;
    #pragma unroll
    for (int k2 = 0; k2 < 8; ++k2) pk.h[k2] = tl[c0 + j + k2][d];
    *(uint4*)(out + ob + (size_t)d * T_ + t0 + c0 + j) = pk.u;
  }
}

// ---------------- 128x128 BT-GEMM (A[M][K] bf16, BT[N][K] bf16) ----------------
// XOR-swizzled LDS. MODE 0: C fp32 plain store. MODE 1: QKV split (Q bf16
// PRE-SCALED by EXP_SC, K bf16, V f16, all [bh][t][d]; V transposed later).
template <int MODE>
__global__ __launch_bounds__(256) void gemm_bt(
    const bf16* __restrict__ A, const bf16* __restrict__ BT,
    float* __restrict__ Cf, bf16* __restrict__ qb, bf16* __restrict__ kb,
    _Float16* __restrict__ vb, int M, int N, int K) {
  __shared__ bf16 As[128 * 64];   // [m][g-swizzled k]
  __shared__ bf16 Bs[128 * 64];   // [n][g-swizzled k]
  const int tid = threadIdx.x;
  const int l = tid & 63, w = tid >> 6;
  const int wm = w >> 1, wn = w & 1;          // 2x2 wave grid, 64x64 C each
  const int m0 = blockIdx.y * 128, n0 = blockIdx.x * 128;
  const int fr = l & 15;                      // fragment row (m or n)
  const int lg = l >> 4;                      // lane granule group 0..3

  v4f acc[4][4] = {};

  for (int kt = 0; kt < K; kt += 64) {
    __syncthreads();
    #pragma unroll
    for (int i = 0; i < 4; ++i) {
      int p = i * 256 + tid;                  // granule index 0..1023
      int row = p >> 3, g = (p & 7) ^ (row & 7);
      gld_lds16(A + (size_t)(m0 + row) * K + kt + g * 8, As + p * 8);
      gld_lds16(BT + (size_t)(n0 + row) * K + kt + g * 8, Bs + p * 8);
    }
    __syncthreads();
    #pragma unroll
    for (int kk = 0; kk < 64; kk += 32) {
      const int gl = (kk >> 3) + lg;          // logical granule 0..7
      bf16x8 af[4], bfr[4];
      #pragma unroll
      for (int i = 0; i < 4; ++i) {
        int row = wm * 64 + i * 16 + fr;
        af[i] = *(const bf16x8*)(As + row * 64 + (gl ^ (fr & 7)) * 8);
      }
      #pragma unroll
      for (int i = 0; i < 4; ++i) {
        int row = wn * 64 + i * 16 + fr;
        bfr[i] = *(const bf16x8*)(Bs + row * 64 + (gl ^ (fr & 7)) * 8);
      }
      #pragma unroll
      for (int mi = 0; mi < 4; ++mi)
        #pragma unroll
        for (int ni = 0; ni < 4; ++ni)
          acc[mi][ni] = __builtin_amdgcn_mfma_f32_16x16x32_bf16(
              af[mi], bfr[ni], acc[mi][ni], 0, 0, 0);
    }
  }

  // Epilogue. C/D layout: col = lane&15, row = (lane>>4)*4 + reg.
  #pragma unroll
  for (int mi = 0; mi < 4; ++mi) {
    #pragma unroll
    for (int ni = 0; ni < 4; ++ni) {
      #pragma unroll
      for (int r = 0; r < 4; ++r) {
        int gm = m0 + wm * 64 + mi * 16 + (l >> 4) * 4 + r;
        int gn = n0 + wn * 64 + ni * 16 + (l & 15);
        float v = acc[mi][ni][r];
        if constexpr (MODE == 0) {
          Cf[(size_t)gm * N + gn] = v;
        } else {
          int b = gm >> 11, t = gm & 2047;            // T=2048
          int s = gn >> 10, h = (gn >> 6) & 15, d = gn & 63;
          size_t bh = (size_t)(b * NH + h);
          if (s == 0)      qb[(bh * T_ + t) * HD + d] = __float2bfloat16(v * EXP_SC);
          else if (s == 1) kb[(bh * T_ + t) * HD + d] = __float2bfloat16(v);
          else             vb[(bh * T_ + t) * HD + d] = (_Float16)v;
        }
      }
    }
  }
}

// ---------------- 128x64 BT-GEMM for the projection ----------------
__global__ __launch_bounds__(256) void gemm_bt_n64(
    const bf16* __restrict__ A, const bf16* __restrict__ BT,
    float* __restrict__ Cf, int M, int N, int K) {
  __shared__ bf16 As[128 * 64];   // 16KB
  __shared__ bf16 Bs[64 * 64];    //  8KB
  const int tid = threadIdx.x;
  const int l = tid & 63, w = tid >> 6;
  const int wm = w >> 1, wn = w & 1;          // 64m x 32n per wave
  const int m0 = blockIdx.y * 128, n0 = blockIdx.x * 64;
  const int fr = l & 15;
  const int lg = l >> 4;

  v4f acc[4][2] = {};

  for (int kt = 0; kt < K; kt += 64) {
    __syncthreads();
    #pragma unroll
    for (int i = 0; i < 4; ++i) {
      int p = i * 256 + tid;
      int row = p >> 3, g = (p & 7) ^ (row & 7);
      gld_lds16(A + (size_t)(m0 + row) * K + kt + g * 8, As + p * 8);
    }
    #pragma unroll
    for (int i = 0; i < 2; ++i) {
      int p = i * 256 + tid;
      int row = p >> 3, g = (p & 7) ^ (row & 7);
      gld_lds16(BT + (size_t)(n0 + row) * K + kt + g * 8, Bs + p * 8);
    }
    __syncthreads();
    #pragma unroll
    for (int kk = 0; kk < 64; kk += 32) {
      const int gl = (kk >> 3) + lg;
      bf16x8 af[4], bfr[2];
      #pragma unroll
      for (int i = 0; i < 4; ++i) {
        int row = wm * 64 + i * 16 + fr;
        af[i] = *(const bf16x8*)(As + row * 64 + (gl ^ (fr & 7)) * 8);
      }
      #pragma unroll
      for (int i = 0; i < 2; ++i) {
        int row = wn * 32 + i * 16 + fr;
        bfr[i] = *(const bf16x8*)(Bs + row * 64 + (gl ^ (fr & 7)) * 8);
      }
      #pragma unroll
      for (int mi = 0; mi < 4; ++mi)
        #pragma unroll
        for (int ni = 0; ni < 2; ++ni)
          acc[mi][ni] = __builtin_amdgcn_mfma_f32_16x16x32_bf16(
              af[mi], bfr[ni], acc[mi][ni], 0, 0, 0);
    }
  }

  #pragma unroll
  for (int mi = 0; mi < 4; ++mi)
    #pragma unroll
    for (int ni = 0; ni < 2; ++ni)
      #pragma unroll
      for (int r = 0; r < 4; ++r) {
        int gm = m0 + wm * 64 + mi * 16 + (l >> 4) * 4 + r;
        int gn = n0 + wn * 32 + ni * 16 + (l & 15);
        Cf[(size_t)gm * N + gn] = acc[mi][ni][r];
      }
}

// ---------------- fused attention: key-split waves + packed-P + K=32 f16 PV ------
// Round-10 proven structure (Kt=128, __syncthreads) + mul-free exp2 (Q is
// pre-scaled by log2(e)/64 in the QKV epilogue). Block 256 = 4 waves, wave
// (qh=w&1, kh=w>>1): 64 q x 64 keys per 128-key tile. Partial O and l are
// purely additive across key halves (no max subtraction; muP 1/64 scale:
// exp2 can't overflow) -> one LDS combine at the end. S^T = K Q^T C-layout
// feeds packed ds_write_b64 of P; PV reads b128 A-frags at full K=32 f16
// rate; row sums via ones-B MFMA. Grid (T/128, B*H), block 256.
__global__ __launch_bounds__(256) void flash_attn(
    const bf16* __restrict__ Qg, const bf16* __restrict__ Kg,
    const _Float16* __restrict__ VTg, bf16* __restrict__ Og) {
  __shared__ char smem[53248];
  bf16*     Ks = (bf16*)smem;                         // [128][64] swizzled, 16KB
  _Float16* Vs = (_Float16*)(smem + 16384);           // [64][128] swizzled, 16KB
  _Float16 (*Ps)[40] = (_Float16(*)[40])(smem + 32768); // [4*64][40], 20KB
  float*    Obuf = (float*)smem;                      // combine alias: [2][64][68]
  float*    Lbuf = (float*)(smem + 34816);            // combine alias: [2][64]

  const int tid = threadIdx.x, l = tid & 63, w = tid >> 6;
  const int qh = w & 1, kh = w >> 1;
  const int fr = l & 15, fk = (l >> 4) * 8, g4 = (l >> 4) * 4, lg = l >> 4;
  const int bh = blockIdx.y, qt = blockIdx.x;
  const int q0 = qt * 128 + qh * 64;           // wave's first q-row
  const size_t base  = (size_t)bh * T_ * HD;   // Q/K base
  const size_t baseV = (size_t)bh * HD * T_;   // V^T base
  _Float16 (*Pw)[40] = Ps + w * 64;            // wave-private P rows

  // Q fragments (B-operand of S^T: n=q, k=d) in registers, loaded once.
  bf16x8 qB[4][2];
  #pragma unroll
  for (int qf = 0; qf < 4; ++qf)
    #pragma unroll
    for (int kki = 0; kki < 2; ++kki)
      qB[qf][kki] = *(const bf16x8*)(
          Qg + base + (size_t)(q0 + qf * 16 + fr) * HD + kki * 32 + fk);

  h8 ones;
  #pragma unroll
  for (int j = 0; j < 8; ++j) ones[j] = (_Float16)1.0f;

  v4f o[4][4] = {};     // partial O: m=q (4 frags), n=d (4 frags)
  v4f lacc[4] = {};     // partial row sums

  for (int kt = 0; kt < T_; kt += 128) {
    __syncthreads();
    #pragma unroll
    for (int i = 0; i < 4; ++i) {
      int p = i * 256 + tid;                   // 1024 granules each
      int krow = p >> 3, kg = (p & 7) ^ (krow & 7);
      gld_lds16(Kg + base + (size_t)(kt + krow) * HD + kg * 8, Ks + p * 8);
      int vrow = p >> 4, vg = (p & 15) ^ (vrow & 15);
      gld_lds16(VTg + baseV + (size_t)vrow * T_ + kt + vg * 8, Vs + p * 8);
    }
    __syncthreads();

    // Wave's 64 keys (half kh) in 2 chunks of 32: S^T -> exp2 -> store -> PV.
    #pragma unroll
    for (int c = 0; c < 2; ++c) {
      const int kkg = kh * 2 + c;              // global 32-key chunk 0..3
      #pragma unroll
      for (int hf = 0; hf < 2; ++hf) {
        const int kf = kkg * 2 + hf;           // global 16-key frag 0..7
        v4f st[4] = {};
        #pragma unroll
        for (int kki = 0; kki < 2; ++kki) {
          int row = kf * 16 + fr;
          bf16x8 ak = *(const bf16x8*)(
              Ks + row * 64 + ((kki * 4 + lg) ^ (fr & 7)) * 8);
          #pragma unroll
          for (int qf = 0; qf < 4; ++qf)
            st[qf] = __builtin_amdgcn_mfma_f32_16x16x32_bf16(
                ak, qB[qf][kki], st[qf], 0, 0, 0);
        }
        #pragma unroll
        for (int qf = 0; qf < 4; ++qf) {
          union { fp16x2 p2[2]; h4 p4; } u;
          u.p2[0] = __builtin_amdgcn_cvt_pkrtz(
              __builtin_amdgcn_exp2f(st[qf][0]),
              __builtin_amdgcn_exp2f(st[qf][1]));
          u.p2[1] = __builtin_amdgcn_cvt_pkrtz(
              __builtin_amdgcn_exp2f(st[qf][2]),
              __builtin_amdgcn_exp2f(st[qf][3]));
          *(h4*)(&Pw[qf * 16 + fr][hf * 16 + g4]) = u.p4;
        }
      }
      h8 ap[4], bv[4];
      #pragma unroll
      for (int qf = 0; qf < 4; ++qf)
        ap[qf] = *(const h8*)(&Pw[qf * 16 + fr][fk]);
      #pragma unroll
      for (int nf = 0; nf < 4; ++nf) {
        int row = nf * 16 + fr;
        bv[nf] = *(const h8*)(Vs + row * 128 + ((kkg * 4 + lg) ^ fr) * 8);
      }
      #pragma unroll
      for (int qf = 0; qf < 4; ++qf) {
        lacc[qf] = __builtin_amdgcn_mfma_f32_16x16x32_f16(
            ap[qf], ones, lacc[qf], 0, 0, 0);
        #pragma unroll
        for (int nf = 0; nf < 4; ++nf)
          o[qf][nf] = __builtin_amdgcn_mfma_f32_16x16x32_f16(
              ap[qf], bv[nf], o[qf][nf], 0, 0, 0);
      }
    }
  }

  // Combine key halves: waves 2,3 dump partials to LDS; waves 0,1 add + store.
  __syncthreads();           // all tiles done; Ks/Vs/Ps now dead
  if (w >= 2) {
    #pragma unroll
    for (int qf = 0; qf < 4; ++qf)
      #pragma unroll
      for (int r = 0; r < 4; ++r) {
        int row = qf * 16 + g4 + r;
        #pragma unroll
        for (int nf = 0; nf < 4; ++nf)
          Obuf[(qh * 64 + row) * 68 + nf * 16 + fr] = o[qf][nf][r];
        if (fr == 0) Lbuf[qh * 64 + row] = lacc[qf][r];
      }
  }
  __syncthreads();
  if (w < 2) {
    int b = bh >> 4, h = bh & 15;
    #pragma unroll
    for (int qf = 0; qf < 4; ++qf) {
      #pragma unroll
      for (int r = 0; r < 4; ++r) {
        int row = qf * 16 + g4 + r;
        float inv = 1.f / (lacc[qf][r] + Lbuf[qh * 64 + row]);
        int t = q0 + row;
        #pragma unroll
        for (int nf = 0; nf < 4; ++nf) {
          float val = o[qf][nf][r] + Obuf[(qh * 64 + row) * 68 + nf * 16 + fr];
          Og[((size_t)(b * T_ + t)) * DM + h * HD + nf * 16 + fr] =
              __float2bfloat16(val * inv);
        }
      }
    }
  }
}

extern "C" void kernel_launch(void* const* d_in, const int* in_sizes, int n_in,
                              void* d_out, int out_size, void* d_ws, size_t ws_size,
                              hipStream_t stream) {
  const float* x     = (const float*)d_in[0];
  const float* Wqkv  = (const float*)d_in[1];
  const float* Wproj = (const float*)d_in[2];
  float* out = (float*)d_out;
  char* ws = (char*)d_ws;

  // Workspace layout (48 MB total). Region 40-48MB double-used: first Vh
  // (f16 V [bh][t][d], consumed by transpose_v), then Ab (flash output).
  bf16*     Xb     = (bf16*)(ws);                        //  8 MB
  bf16*     WqkvT  = (bf16*)(ws + (size_t)( 8u << 20));  //  6 MB
  bf16*     WprojT = (bf16*)(ws + (size_t)(14u << 20));  //  2 MB
  bf16*     Qb     = (bf16*)(ws + (size_t)(16u << 20));  //  8 MB
  bf16*     Kb     = (bf16*)(ws + (size_t)(24u << 20));  //  8 MB
  _Float16* VTh    = (_Float16*)(ws + (size_t)(32u << 20)); // 8 MB
  _Float16* Vh     = (_Float16*)(ws + (size_t)(40u << 20)); // 8 MB (temp)
  bf16*     Ab     = (bf16*)(ws + (size_t)(40u << 20));  //  8 MB (overlay)

  prep<<<8192, 256, 0, stream>>>(x, Wqkv, Wproj, Xb, WqkvT, WprojT);

  gemm_bt<1><<<dim3(N_QKV / 128, M_ / 128), 256, 0, stream>>>(
      Xb, WqkvT, nullptr, Qb, Kb, Vh, M_, N_QKV, DM);

  transpose_v<<<dim3(T_ / 64, B_ * NH), 256, 0, stream>>>(Vh, VTh);

  flash_attn<<<dim3(T_ / 128, B_ * NH), 256, 0, stream>>>(Qb, Kb, VTh, Ab);

  gemm_bt_n64<<<dim3(DM / 64, M_ / 128), 256, 0, stream>>>(
      Ab, WprojT, out, M_, DM, DM);
}